// Round 1
// baseline (24107.008 us; speedup 1.0000x reference)
//
#include <hip/hip_runtime.h>
#include <math.h>

#define BATCH 64
#define TT 256
#define IN_DIM 512
#define H 1024
#define G4 4096

// ---------------------------------------------------------------------------
// zero-fill
__global__ void zero_kernel(float* __restrict__ p, int n) {
    int i = blockIdx.x * 256 + threadIdx.x;
    if (i < n) p[i] = 0.f;
}

// ---------------------------------------------------------------------------
// xp[ti][n][b] = sum_k A(m',k) * W[n][k] + bias[n],  m' = ti*64 + b
// ALAYOUT 0: A = x, element (m',k) at A[(b*TT + t0 + ti)*K + k]        (row-major x)
// ALAYOUT 1: A = ysT, element (m',k) at A[((t0+ti)*H + k)*BATCH + b]   (transposed ys)
template<int ALAYOUT>
__global__ __launch_bounds__(256) void gemm_xproj(
    const float* __restrict__ A, const float* __restrict__ W,
    const float* __restrict__ bias, float* __restrict__ C,
    int K, int t0) {
    __shared__ float As[16][132];
    __shared__ float Bs[16][132];
    const int tid = threadIdx.x;
    const int tm = tid & 15, tn = tid >> 4;
    const int mbase = blockIdx.x * 128;
    const int nbase = blockIdx.y * 128;

    float acc[8][8];
#pragma unroll
    for (int i = 0; i < 8; ++i)
#pragma unroll
        for (int j = 0; j < 8; ++j) acc[i][j] = 0.f;

    for (int k0 = 0; k0 < K; k0 += 16) {
#pragma unroll
        for (int p = 0; p < 2; ++p) {
            int idx = p * 256 + tid;
            // ---- A tile -> As[k][m]
            if (ALAYOUT == 0) {
                int row = idx >> 2, kv = idx & 3;
                int m = mbase + row;
                int bb = m & 63, ti = m >> 6;
                const float4 v = *(const float4*)(A + (size_t)(bb * TT + t0 + ti) * K + k0 + kv * 4);
                As[kv * 4 + 0][row] = v.x;
                As[kv * 4 + 1][row] = v.y;
                As[kv * 4 + 2][row] = v.z;
                As[kv * 4 + 3][row] = v.w;
            } else {
                int kk = idx >> 5, mv = idx & 31;
                int m = mbase + mv * 4;
                int bb = m & 63, ti = m >> 6;
                const float4 v = *(const float4*)(A + ((size_t)(t0 + ti) * H + k0 + kk) * BATCH + bb);
                *(float4*)&As[kk][mv * 4] = v;
            }
            // ---- W tile -> Bs[k][n]  (W row-major [G4][K])
            {
                int row = idx >> 2, kv = idx & 3;
                const float4 v = *(const float4*)(W + (size_t)(nbase + row) * K + k0 + kv * 4);
                Bs[kv * 4 + 0][row] = v.x;
                Bs[kv * 4 + 1][row] = v.y;
                Bs[kv * 4 + 2][row] = v.z;
                Bs[kv * 4 + 3][row] = v.w;
            }
        }
        __syncthreads();
#pragma unroll
        for (int kk = 0; kk < 16; ++kk) {
            float4 a0 = *(const float4*)&As[kk][tm * 8];
            float4 a1 = *(const float4*)&As[kk][tm * 8 + 4];
            float4 b0 = *(const float4*)&Bs[kk][tn * 8];
            float4 b1 = *(const float4*)&Bs[kk][tn * 8 + 4];
            float av[8] = {a0.x, a0.y, a0.z, a0.w, a1.x, a1.y, a1.z, a1.w};
            float bv[8] = {b0.x, b0.y, b0.z, b0.w, b1.x, b1.y, b1.z, b1.w};
#pragma unroll
            for (int i = 0; i < 8; ++i)
#pragma unroll
                for (int j = 0; j < 8; ++j) acc[i][j] += av[i] * bv[j];
        }
        __syncthreads();
    }
    // epilogue: C[ti][n][b], 8 consecutive m' = 8 consecutive b within one ti
    const int mloc = tm * 8;
    const int ti = (mbase + mloc) >> 6;
    const int bb = mloc & 63;
    float* crow = C + (size_t)ti * G4 * BATCH;
#pragma unroll
    for (int ni = 0; ni < 8; ++ni) {
        int n = nbase + tn * 8 + ni;
        float bsv = bias[n];
        float4 v0 = make_float4(acc[0][ni] + bsv, acc[1][ni] + bsv, acc[2][ni] + bsv, acc[3][ni] + bsv);
        float4 v1 = make_float4(acc[4][ni] + bsv, acc[5][ni] + bsv, acc[6][ni] + bsv, acc[7][ni] + bsv);
        *(float4*)(crow + (size_t)n * BATCH + bb) = v0;
        *(float4*)(crow + (size_t)n * BATCH + bb + 4) = v1;
    }
}

// ---------------------------------------------------------------------------
// One LSTM timestep. 256 blocks, each owns 4 hidden units (16 gate rows).
// gates[b, gi*H + j] = xp_t[row][b] + sum_k h[k][b] * Whh[row][k]
// W rows streamed via wave-uniform scalar loads (s_load), h staged in LDS.
__global__ __launch_bounds__(256) void lstm_step_kernel(
    const float* __restrict__ xp_t,   // [G4][BATCH]
    const float* __restrict__ Whh,    // [G4][H]
    const float* __restrict__ hT_in,  // [H][BATCH]
    float* __restrict__ cT,           // [H][BATCH] in/out
    float* __restrict__ hT_out,       // [H][BATCH]
    float* __restrict__ ysT_t) {      // [H][BATCH] or null
    __shared__ float Hs[128][64];
    __shared__ float gbuf[4][4][64];  // [gate][hu][b]
    const int tid = threadIdx.x;
    const int b = tid & 63;
    const int rg = __builtin_amdgcn_readfirstlane(tid >> 6);  // gate index, wave-uniform
    const int hu_base = blockIdx.x * 4;

    const float* w0 = Whh + (size_t)(rg * H + hu_base + 0) * H;
    const float* w1 = w0 + H;
    const float* w2 = w0 + 2 * H;
    const float* w3 = w0 + 3 * H;

    float acc0 = xp_t[(size_t)(rg * H + hu_base + 0) * BATCH + b];
    float acc1 = xp_t[(size_t)(rg * H + hu_base + 1) * BATCH + b];
    float acc2 = xp_t[(size_t)(rg * H + hu_base + 2) * BATCH + b];
    float acc3 = xp_t[(size_t)(rg * H + hu_base + 3) * BATCH + b];

    for (int k0 = 0; k0 < H; k0 += 128) {
#pragma unroll
        for (int p = 0; p < 8; ++p) {
            int idx = p * 256 + tid;
            int kk = idx >> 4, bv = idx & 15;
            *(float4*)&Hs[kk][bv * 4] = *(const float4*)(hT_in + (size_t)(k0 + kk) * BATCH + bv * 4);
        }
        __syncthreads();
#pragma unroll
        for (int kk = 0; kk < 128; kk += 4) {
            float4 W0 = *(const float4*)(w0 + k0 + kk);
            float4 W1 = *(const float4*)(w1 + k0 + kk);
            float4 W2 = *(const float4*)(w2 + k0 + kk);
            float4 W3 = *(const float4*)(w3 + k0 + kk);
            float h0v = Hs[kk + 0][b];
            float h1v = Hs[kk + 1][b];
            float h2v = Hs[kk + 2][b];
            float h3v = Hs[kk + 3][b];
            acc0 += h0v * W0.x + h1v * W0.y + h2v * W0.z + h3v * W0.w;
            acc1 += h0v * W1.x + h1v * W1.y + h2v * W1.z + h3v * W1.w;
            acc2 += h0v * W2.x + h1v * W2.y + h2v * W2.z + h3v * W2.w;
            acc3 += h0v * W3.x + h1v * W3.y + h2v * W3.z + h3v * W3.w;
        }
        __syncthreads();
    }

    gbuf[rg][0][b] = acc0;
    gbuf[rg][1][b] = acc1;
    gbuf[rg][2][b] = acc2;
    gbuf[rg][3][b] = acc3;
    __syncthreads();
    {
        int hu = tid >> 6;
        int j = hu_base + hu;
        float iv = gbuf[0][hu][b];
        float fv = gbuf[1][hu][b];
        float gv = gbuf[2][hu][b];
        float ov = gbuf[3][hu][b];
        float is = 1.f / (1.f + expf(-iv));
        float fs = 1.f / (1.f + expf(-fv));
        float gt = tanhf(gv);
        float os = 1.f / (1.f + expf(-ov));
        float cold = cT[(size_t)j * BATCH + b];
        float cnew = fs * cold + is * gt;
        float hnew = os * tanhf(cnew);
        cT[(size_t)j * BATCH + b] = cnew;
        hT_out[(size_t)j * BATCH + b] = hnew;
        if (ysT_t) ysT_t[(size_t)j * BATCH + b] = hnew;
    }
}

// ---------------------------------------------------------------------------
// out[b][o] = sum_j hT[j][b] * Wfc[o][j] + bfc[o]
__global__ __launch_bounds__(256) void fc_kernel(
    const float* __restrict__ hT, const float* __restrict__ Wfc,
    const float* __restrict__ bfc, float* __restrict__ out) {
    int tid = threadIdx.x;
    int b = tid & 63;
    int oo = __builtin_amdgcn_readfirstlane(tid >> 6);
    int o = blockIdx.x * 4 + oo;
    const float* wr = Wfc + (size_t)o * H;
    float acc = 0.f;
#pragma unroll 8
    for (int j = 0; j < H; j += 4) {
        float4 w = *(const float4*)(wr + j);
        acc += hT[(size_t)(j + 0) * BATCH + b] * w.x
             + hT[(size_t)(j + 1) * BATCH + b] * w.y
             + hT[(size_t)(j + 2) * BATCH + b] * w.z
             + hT[(size_t)(j + 3) * BATCH + b] * w.w;
    }
    out[(size_t)b * 512 + o] = acc + bfc[o];
}

// ---------------------------------------------------------------------------
extern "C" void kernel_launch(void* const* d_in, const int* in_sizes, int n_in,
                              void* d_out, int out_size, void* d_ws, size_t ws_size,
                              hipStream_t stream) {
    const float* x    = (const float*)d_in[0];
    const float* Wih0 = (const float*)d_in[1];
    const float* Whh0 = (const float*)d_in[2];
    const float* b0   = (const float*)d_in[3];
    const float* Wih1 = (const float*)d_in[4];
    const float* Whh1 = (const float*)d_in[5];
    const float* b1   = (const float*)d_in[6];
    const float* Wfc  = (const float*)d_in[7];
    const float* bfc  = (const float*)d_in[8];
    float* out = (float*)d_out;

    // workspace: xp chunk + ysT + hT0/hT1/cT  (runtime-sized chunk)
    auto need = [](int ch) {
        return ((size_t)ch * G4 * BATCH + (size_t)TT * H * BATCH + 3 * (size_t)H * BATCH) * sizeof(float);
    };
    int CH = 32;
    if (ws_size < need(32)) CH = 8;
    if (ws_size < need(8)) CH = 2;

    float* ws  = (float*)d_ws;
    float* xp  = ws;
    float* ysT = xp + (size_t)CH * G4 * BATCH;
    float* hT0 = ysT + (size_t)TT * H * BATCH;
    float* hT1 = hT0 + (size_t)H * BATCH;
    float* cT  = hT1 + (size_t)H * BATCH;

    for (int layer = 0; layer < 2; ++layer) {
        zero_kernel<<<dim3((3 * H * BATCH + 255) / 256), 256, 0, stream>>>(hT0, 3 * H * BATCH);
        const float* Whh = layer ? Whh1 : Whh0;
        const int nch = TT / CH;
        for (int c = 0; c < nch; ++c) {
            int t0 = c * CH;
            dim3 g(CH * 64 / 128, 32);
            if (layer == 0)
                gemm_xproj<0><<<g, 256, 0, stream>>>(x, Wih0, b0, xp, IN_DIM, t0);
            else
                gemm_xproj<1><<<g, 256, 0, stream>>>(ysT, Wih1, b1, xp, H, t0);
            for (int ti = 0; ti < CH; ++ti) {
                int tt = t0 + ti;
                const float* hin = (tt & 1) ? hT1 : hT0;
                float* hout      = (tt & 1) ? hT0 : hT1;
                float* yst = (layer == 0) ? (ysT + (size_t)tt * H * BATCH) : nullptr;
                lstm_step_kernel<<<256, 256, 0, stream>>>(
                    xp + (size_t)ti * G4 * BATCH, Whh, hin, cT, hout, yst);
            }
        }
    }
    // t=255 (odd) wrote hT0 -> final hidden state
    fc_kernel<<<128, 256, 0, stream>>>(hT0, Wfc, bfc, out);
}

// Round 2
// 21216.812 us; speedup vs baseline: 1.1362x; 1.1362x over previous
//
#include <hip/hip_runtime.h>
#include <math.h>

#define BATCH 64
#define TT 256
#define IN_DIM 512
#define H 1024
#define G4 4096

// ---------------------------------------------------------------------------
__global__ void zero_kernel(float* __restrict__ p, int n) {
    int i = blockIdx.x * 256 + threadIdx.x;
    if (i < n) p[i] = 0.f;
}

// ---------------------------------------------------------------------------
// xp[ti][n][b] = sum_k A(m',k) * W[n][k] + bias[n],  m' = ti*64 + b
// ALAYOUT 0: A = x, element (m',k) at A[(b*TT + t0 + ti)*K + k]
// ALAYOUT 1: A = ysT, element (m',k) at A[((t0+ti)*H + k)*BATCH + b]
template<int ALAYOUT>
__global__ __launch_bounds__(256) void gemm_xproj(
    const float* __restrict__ A, const float* __restrict__ W,
    const float* __restrict__ bias, float* __restrict__ C,
    int K, int t0) {
    __shared__ float As[16][132];
    __shared__ float Bs[16][132];
    const int tid = threadIdx.x;
    const int tm = tid & 15, tn = tid >> 4;
    const int mbase = blockIdx.x * 128;
    const int nbase = blockIdx.y * 128;

    float acc[8][8];
#pragma unroll
    for (int i = 0; i < 8; ++i)
#pragma unroll
        for (int j = 0; j < 8; ++j) acc[i][j] = 0.f;

    for (int k0 = 0; k0 < K; k0 += 16) {
#pragma unroll
        for (int p = 0; p < 2; ++p) {
            int idx = p * 256 + tid;
            if (ALAYOUT == 0) {
                int row = idx >> 2, kv = idx & 3;
                int m = mbase + row;
                int bb = m & 63, ti = m >> 6;
                const float4 v = *(const float4*)(A + (size_t)(bb * TT + t0 + ti) * K + k0 + kv * 4);
                As[kv * 4 + 0][row] = v.x;
                As[kv * 4 + 1][row] = v.y;
                As[kv * 4 + 2][row] = v.z;
                As[kv * 4 + 3][row] = v.w;
            } else {
                int kk = idx >> 5, mv = idx & 31;
                int m = mbase + mv * 4;
                int bb = m & 63, ti = m >> 6;
                const float4 v = *(const float4*)(A + ((size_t)(t0 + ti) * H + k0 + kk) * BATCH + bb);
                *(float4*)&As[kk][mv * 4] = v;
            }
            {
                int row = idx >> 2, kv = idx & 3;
                const float4 v = *(const float4*)(W + (size_t)(nbase + row) * K + k0 + kv * 4);
                Bs[kv * 4 + 0][row] = v.x;
                Bs[kv * 4 + 1][row] = v.y;
                Bs[kv * 4 + 2][row] = v.z;
                Bs[kv * 4 + 3][row] = v.w;
            }
        }
        __syncthreads();
#pragma unroll
        for (int kk = 0; kk < 16; ++kk) {
            float4 a0 = *(const float4*)&As[kk][tm * 8];
            float4 a1 = *(const float4*)&As[kk][tm * 8 + 4];
            float4 b0 = *(const float4*)&Bs[kk][tn * 8];
            float4 b1 = *(const float4*)&Bs[kk][tn * 8 + 4];
            float av[8] = {a0.x, a0.y, a0.z, a0.w, a1.x, a1.y, a1.z, a1.w};
            float bv[8] = {b0.x, b0.y, b0.z, b0.w, b1.x, b1.y, b1.z, b1.w};
#pragma unroll
            for (int i = 0; i < 8; ++i)
#pragma unroll
                for (int j = 0; j < 8; ++j) acc[i][j] += av[i] * bv[j];
        }
        __syncthreads();
    }
    const int mloc = tm * 8;
    const int ti = (mbase + mloc) >> 6;
    const int bb = mloc & 63;
    float* crow = C + (size_t)ti * G4 * BATCH;
#pragma unroll
    for (int ni = 0; ni < 8; ++ni) {
        int n = nbase + tn * 8 + ni;
        float bsv = bias[n];
        float4 v0 = make_float4(acc[0][ni] + bsv, acc[1][ni] + bsv, acc[2][ni] + bsv, acc[3][ni] + bsv);
        float4 v1 = make_float4(acc[4][ni] + bsv, acc[5][ni] + bsv, acc[6][ni] + bsv, acc[7][ni] + bsv);
        *(float4*)(crow + (size_t)n * BATCH + bb) = v0;
        *(float4*)(crow + (size_t)n * BATCH + bb + 4) = v1;
    }
}

// ---------------------------------------------------------------------------
// One LSTM timestep. 256 blocks x 256 threads. Block owns 4 hidden units
// (16 gate rows, flat i = g*4+hu). Wave w: rows ibase=(w&1)*8..+8,
// k-half kh=(w>>1). h staged transposed in LDS as Hs[b][k] with XOR swizzle
// (k ^ ((b&31)<<2)) so compute reads are single ds_read_b128 per 4k,
// conflict-free. W rows via wave-uniform pointers (s_load path).
__global__ __launch_bounds__(256) void lstm_step_kernel(
    const float* __restrict__ xp_t,   // [G4][BATCH]
    const float* __restrict__ Whh,    // [G4][H]
    const float* __restrict__ hT_in,  // [H][BATCH]
    float* __restrict__ cT,           // [H][BATCH] in/out
    float* __restrict__ hT_out,       // [H][BATCH]
    float* __restrict__ ysT_t) {      // [H][BATCH] or null
    __shared__ float lds[16384];      // 64KB: 2 halves x [64 b][128 k]; tail reused as gbuf
    const int tid = threadIdx.x;
    const int b = tid & 63;
    const int w = __builtin_amdgcn_readfirstlane(tid >> 6);
    const int kh = w >> 1;           // k half
    const int ibase = (w & 1) * 8;   // flat row group
    const int hu_base = blockIdx.x * 4;

    // W row pointers (wave-uniform)
    const float* wr[8];
#pragma unroll
    for (int ii = 0; ii < 8; ++ii) {
        int i = ibase + ii;
        int row = (i >> 2) * H + hu_base + (i & 3);
        wr[ii] = Whh + (size_t)row * H + kh * 512;
    }

    float acc[8];
#pragma unroll
    for (int ii = 0; ii < 8; ++ii) acc[ii] = 0.f;

    const int shalf = tid >> 7;        // staging: which k-half this thread fills
    const int kgp = (tid >> 6) & 1;    // k-group parity
    const int rbase = kh * 8192 + (b << 7);

    for (int c = 0; c < 4; ++c) {
        // ---- stage chunk c (128 k) of both halves, transposed + swizzled
#pragma unroll 4
        for (int s = 0; s < 16; ++s) {
            int kg = kgp + s * 2;                        // 0..31
            int kbase = shalf * 512 + c * 128 + kg * 4;  // global k
            float4 v;
            v.x = hT_in[(size_t)(kbase + 0) * BATCH + b];
            v.y = hT_in[(size_t)(kbase + 1) * BATCH + b];
            v.z = hT_in[(size_t)(kbase + 2) * BATCH + b];
            v.w = hT_in[(size_t)(kbase + 3) * BATCH + b];
            *(float4*)&lds[shalf * 8192 + ((b << 7) | ((kg * 4) ^ ((b & 31) << 2)))] = v;
        }
        __syncthreads();
        // ---- compute on this wave's half
#pragma unroll 2
        for (int kk = 0; kk < 128; kk += 4) {
            float4 h4 = *(const float4*)&lds[rbase + (kk ^ ((b & 31) << 2))];
#pragma unroll
            for (int ii = 0; ii < 8; ++ii) {
                float4 wv = *(const float4*)(wr[ii] + c * 128 + kk);
                acc[ii] += h4.x * wv.x + h4.y * wv.y + h4.z * wv.z + h4.w * wv.w;
            }
        }
        __syncthreads();
    }

    // ---- reduce the two k-halves via LDS (reuse lds as gbuf[2][16][64])
#pragma unroll
    for (int ii = 0; ii < 8; ++ii)
        lds[kh * 1024 + (ibase + ii) * 64 + b] = acc[ii];
    __syncthreads();
    {
        int hu = tid >> 6;             // 0..3
        int j = hu_base + hu;
        float gg[4];
#pragma unroll
        for (int g = 0; g < 4; ++g) {
            int i = g * 4 + hu;
            gg[g] = lds[i * 64 + b] + lds[1024 + i * 64 + b]
                  + xp_t[(size_t)(g * H + j) * BATCH + b];
        }
        float is = 1.f / (1.f + expf(-gg[0]));
        float fs = 1.f / (1.f + expf(-gg[1]));
        float gt = tanhf(gg[2]);
        float os = 1.f / (1.f + expf(-gg[3]));
        float cold = cT[(size_t)j * BATCH + b];
        float cnew = fs * cold + is * gt;
        float hnew = os * tanhf(cnew);
        cT[(size_t)j * BATCH + b] = cnew;
        hT_out[(size_t)j * BATCH + b] = hnew;
        if (ysT_t) ysT_t[(size_t)j * BATCH + b] = hnew;
    }
}

// ---------------------------------------------------------------------------
__global__ __launch_bounds__(256) void fc_kernel(
    const float* __restrict__ hT, const float* __restrict__ Wfc,
    const float* __restrict__ bfc, float* __restrict__ out) {
    int tid = threadIdx.x;
    int b = tid & 63;
    int oo = __builtin_amdgcn_readfirstlane(tid >> 6);
    int o = blockIdx.x * 4 + oo;
    const float* wr = Wfc + (size_t)o * H;
    float acc = 0.f;
#pragma unroll 8
    for (int j = 0; j < H; j += 4) {
        float4 w = *(const float4*)(wr + j);
        acc += hT[(size_t)(j + 0) * BATCH + b] * w.x
             + hT[(size_t)(j + 1) * BATCH + b] * w.y
             + hT[(size_t)(j + 2) * BATCH + b] * w.z
             + hT[(size_t)(j + 3) * BATCH + b] * w.w;
    }
    out[(size_t)b * 512 + o] = acc + bfc[o];
}

// ---------------------------------------------------------------------------
extern "C" void kernel_launch(void* const* d_in, const int* in_sizes, int n_in,
                              void* d_out, int out_size, void* d_ws, size_t ws_size,
                              hipStream_t stream) {
    const float* x    = (const float*)d_in[0];
    const float* Wih0 = (const float*)d_in[1];
    const float* Whh0 = (const float*)d_in[2];
    const float* b0   = (const float*)d_in[3];
    const float* Wih1 = (const float*)d_in[4];
    const float* Whh1 = (const float*)d_in[5];
    const float* b1   = (const float*)d_in[6];
    const float* Wfc  = (const float*)d_in[7];
    const float* bfc  = (const float*)d_in[8];
    float* out = (float*)d_out;

    auto need = [](int ch) {
        return ((size_t)ch * G4 * BATCH + (size_t)TT * H * BATCH + 3 * (size_t)H * BATCH) * sizeof(float);
    };
    int CH = 32;
    if (ws_size < need(32)) CH = 8;
    if (ws_size < need(8)) CH = 2;

    float* ws  = (float*)d_ws;
    float* xp  = ws;
    float* ysT = xp + (size_t)CH * G4 * BATCH;
    float* hT0 = ysT + (size_t)TT * H * BATCH;
    float* hT1 = hT0 + (size_t)H * BATCH;
    float* cT  = hT1 + (size_t)H * BATCH;

    for (int layer = 0; layer < 2; ++layer) {
        zero_kernel<<<dim3((3 * H * BATCH + 255) / 256), 256, 0, stream>>>(hT0, 3 * H * BATCH);
        const float* Whh = layer ? Whh1 : Whh0;
        const int nch = TT / CH;
        for (int c = 0; c < nch; ++c) {
            int t0 = c * CH;
            dim3 g(CH * 64 / 128, 32);
            if (layer == 0)
                gemm_xproj<0><<<g, 256, 0, stream>>>(x, Wih0, b0, xp, IN_DIM, t0);
            else
                gemm_xproj<1><<<g, 256, 0, stream>>>(ysT, Wih1, b1, xp, H, t0);
            for (int ti = 0; ti < CH; ++ti) {
                int tt = t0 + ti;
                const float* hin = (tt & 1) ? hT1 : hT0;
                float* hout      = (tt & 1) ? hT0 : hT1;
                float* yst = (layer == 0) ? (ysT + (size_t)tt * H * BATCH) : nullptr;
                lstm_step_kernel<<<256, 256, 0, stream>>>(
                    xp + (size_t)ti * G4 * BATCH, Whh, hin, cT, hout, yst);
            }
        }
    }
    fc_kernel<<<128, 256, 0, stream>>>(hT0, Wfc, bfc, out);
}